// Round 4
// baseline (6975.291 us; speedup 1.0000x reference)
//
#include <hip/hip_runtime.h>
#include <stdint.h>

typedef unsigned short u16;
typedef __attribute__((ext_vector_type(8))) short short8;
typedef __attribute__((ext_vector_type(4))) float f32x4;

#define SWZ(r) (((r) & 7) << 4)
#define SCALE 0.125f

__device__ __forceinline__ u16 f2bf(float f) {
  unsigned int x = __float_as_uint(f);
  x += 0x7fffu + ((x >> 16) & 1u);
  return (u16)(x >> 16);
}

__device__ __forceinline__ float bf2f(u16 u) {
  return __uint_as_float(((unsigned int)u) << 16);
}

__device__ __forceinline__ f32x4 mfma16(short8 a, short8 b, f32x4 c) {
  return __builtin_amdgcn_mfma_f32_16x16x32_bf16(a, b, c, 0, 0, 0);
}

__device__ __forceinline__ void gload_lds16(const u16* g, u16* l) {
  __builtin_amdgcn_global_load_lds(
      (const __attribute__((address_space(1))) unsigned int*)g,
      (__attribute__((address_space(3))) unsigned int*)l, 16, 0, 0);
}

// ---------------- weight conversion: 4x [1024x1024] f32 -> bf16 ----------------
__global__ __launch_bounds__(256) void cvt_w_kernel(
    const float* __restrict__ s0, const float* __restrict__ s1,
    const float* __restrict__ s2, const float* __restrict__ s3,
    u16* __restrict__ dst) {
  int bx = blockIdx.x;
  int mi = bx >> 9;  // 512 blocks per matrix
  const float* s = s0;
  if (mi == 1) s = s1;
  else if (mi == 2) s = s2;
  else if (mi == 3) s = s3;
  size_t idx = (size_t)((bx & 511) * 256 + threadIdx.x) * 8;
  float4 a = *(const float4*)(s + idx);
  float4 b = *(const float4*)(s + idx + 4);
  short8 v;
  v[0] = (short)f2bf(a.x); v[1] = (short)f2bf(a.y);
  v[2] = (short)f2bf(a.z); v[3] = (short)f2bf(a.w);
  v[4] = (short)f2bf(b.x); v[5] = (short)f2bf(b.y);
  v[6] = (short)f2bf(b.z); v[7] = (short)f2bf(b.w);
  *(short8*)(dst + (size_t)mi * 1048576 + idx) = v;
}

// ---------------- GEMM: C[r,o] = sum_d A[r,d]*W[o,d] + bias[o] ----------------
// A: [nrows,1024] (f32 or bf16), W: [1024,1024] bf16 row-major, C: [nrows,1024]
// tile 128x128, BK=64, 4 waves (2x2), 16x16x32 bf16 MFMA, XOR-swizzled LDS.
// BUGFIX r4: staging loops must cover 128 rows -> 4 phases (1024x16B = 16KB),
// not 2. Rows 64..127 of Bs/As were previously uninitialized -> NaN.
template <bool A_F32, bool OUT_F32>
__global__ __launch_bounds__(256, 2) void gemm_bias_kernel(
    const void* __restrict__ Av, const u16* __restrict__ B,
    const float* __restrict__ bias, void* __restrict__ Cv, int nrows) {
  __shared__ __attribute__((aligned(16))) u16 As[128 * 64];
  __shared__ __attribute__((aligned(16))) u16 Bs[128 * 64];
  const int tid = threadIdx.x;
  const int lane = tid & 63;
  const int w = tid >> 6;
  const int wr = w >> 1, wc = w & 1;
  const int l15 = lane & 15, lg = lane >> 4;
  const int brow = blockIdx.y * 128;
  const int bcol = blockIdx.x * 128;

  f32x4 acc[4][4] = {};

  for (int k0 = 0; k0 < 1024; k0 += 64) {
    // stage B (bf16) via global_load_lds: linear dest + inverse-swizzled source
#pragma unroll
    for (int p = 0; p < 4; ++p) {
      int flat = p * 256 + tid;   // [0,1024)
      int row = flat >> 3;        // [0,128)
      int cb = (flat & 7) * 16;
      int scb = cb ^ SWZ(row);
      const u16* src = B + (size_t)(bcol + row) * 1024 + k0 + (scb >> 1);
      gload_lds16(src, Bs + (size_t)flat * 8);
    }
    if constexpr (A_F32) {
      const float* Af = (const float*)Av;
#pragma unroll
      for (int p = 0; p < 4; ++p) {
        int flat = p * 256 + tid;
        int row = flat >> 3;
        int c8 = flat & 7;
        const float* src = Af + (size_t)(brow + row) * 1024 + k0 + c8 * 8;
        float4 v0 = ((const float4*)src)[0];
        float4 v1 = ((const float4*)src)[1];
        short8 sv;
        sv[0] = (short)f2bf(v0.x); sv[1] = (short)f2bf(v0.y);
        sv[2] = (short)f2bf(v0.z); sv[3] = (short)f2bf(v0.w);
        sv[4] = (short)f2bf(v1.x); sv[5] = (short)f2bf(v1.y);
        sv[6] = (short)f2bf(v1.z); sv[7] = (short)f2bf(v1.w);
        *(short8*)((char*)As + row * 128 + ((c8 * 16) ^ SWZ(row))) = sv;
      }
    } else {
      const u16* Ab = (const u16*)Av;
#pragma unroll
      for (int p = 0; p < 4; ++p) {
        int flat = p * 256 + tid;
        int row = flat >> 3;
        int cb = (flat & 7) * 16;
        int scb = cb ^ SWZ(row);
        const u16* src = Ab + (size_t)(brow + row) * 1024 + k0 + (scb >> 1);
        gload_lds16(src, As + (size_t)flat * 8);
      }
    }
    __syncthreads();

    short8 af[4][2], bfr[4][2];
#pragma unroll
    for (int i = 0; i < 4; ++i) {
#pragma unroll
      for (int kk = 0; kk < 2; ++kk) {
        int ar = wr * 64 + i * 16 + l15;
        af[i][kk] = *(const short8*)((const char*)As + ar * 128 +
                                     ((kk * 64 + lg * 16) ^ SWZ(ar)));
        int br = wc * 64 + i * 16 + l15;
        bfr[i][kk] = *(const short8*)((const char*)Bs + br * 128 +
                                      ((kk * 64 + lg * 16) ^ SWZ(br)));
      }
    }
#pragma unroll
    for (int i = 0; i < 4; ++i)
#pragma unroll
      for (int j = 0; j < 4; ++j)
#pragma unroll
        for (int kk = 0; kk < 2; ++kk)
          acc[i][j] = mfma16(af[i][kk], bfr[j][kk], acc[i][j]);
    __syncthreads();
  }

#pragma unroll
  for (int j = 0; j < 4; ++j) {
    int col = bcol + wc * 64 + j * 16 + l15;
    float bv = bias[col];
#pragma unroll
    for (int i = 0; i < 4; ++i) {
      int row0 = brow + wr * 64 + i * 16 + lg * 4;
#pragma unroll
      for (int r = 0; r < 4; ++r) {
        float v = acc[i][j][r] + bv;
        if constexpr (OUT_F32)
          ((float*)Cv)[(size_t)(row0 + r) * 1024 + col] = v;
        else
          ((u16*)Cv)[(size_t)(row0 + r) * 1024 + col] = f2bf(v);
      }
    }
  }
}

// ---------------- simple (correctness-first) attention ----------------
// One block per (m_local, h); thread t<128 owns q-row t. K/V tiles staged
// linearly in LDS; compute reads are block-uniform (LDS broadcast).
// No infinities anywhere: masked bias = -1e30.
__global__ __launch_bounds__(256, 1) void attn_simple_kernel(
    const u16* __restrict__ Q, const u16* __restrict__ Kp,
    const u16* __restrict__ Vp, const int* __restrict__ mask,
    u16* __restrict__ AO, int S, int mbase) {
  __shared__ __attribute__((aligned(16))) u16 Ks[64 * 64];
  __shared__ __attribute__((aligned(16))) u16 Vs[64 * 64];
  __shared__ float mbs[64];

  const int tid = threadIdx.x;
  const int ml = blockIdx.x >> 4;  // local m in [0,8)
  const int h = blockIdx.x & 15;
  const int mg = mbase + ml;

  float q[64], o[64];
  float mrun = -1e30f, lrun = 0.0f;
  if (tid < 128) {
#pragma unroll
    for (int d8 = 0; d8 < 8; ++d8) {
      short8 v = *(const short8*)(Q + (size_t)(mg * 128 + tid) * 1024 + h * 64 + d8 * 8);
#pragma unroll
      for (int j = 0; j < 8; ++j) {
        q[d8 * 8 + j] = bf2f((u16)v[j]);
        o[d8 * 8 + j] = 0.0f;
      }
    }
  }

  const size_t kvbase = (size_t)ml * S * 1024 + h * 64;

  for (int st = 0; st < S; st += 64) {
    if (tid < 64)
      mbs[tid] = (mask[(size_t)mg * S + st + tid] > 0) ? 0.0f : -1e30f;
#pragma unroll
    for (int p = 0; p < 2; ++p) {
      int flat = p * 256 + tid;
      int row = flat >> 3, c = flat & 7;
      *(short8*)(Ks + row * 64 + c * 8) =
          *(const short8*)(Kp + kvbase + (size_t)(st + row) * 1024 + c * 8);
      *(short8*)(Vs + row * 64 + c * 8) =
          *(const short8*)(Vp + kvbase + (size_t)(st + row) * 1024 + c * 8);
    }
    __syncthreads();

    if (tid < 128) {
      for (int s = 0; s < 64; ++s) {
        float a0 = 0.f, a1 = 0.f, a2 = 0.f, a3 = 0.f;
#pragma unroll
        for (int d = 0; d < 64; d += 4) {
          a0 += q[d + 0] * bf2f(Ks[s * 64 + d + 0]);
          a1 += q[d + 1] * bf2f(Ks[s * 64 + d + 1]);
          a2 += q[d + 2] * bf2f(Ks[s * 64 + d + 2]);
          a3 += q[d + 3] * bf2f(Ks[s * 64 + d + 3]);
        }
        float sc = ((a0 + a1) + (a2 + a3)) * SCALE + mbs[s];
        float mnew = fmaxf(mrun, sc);
        float corr = __expf(mrun - mnew);  // finite: mrun,mnew >= -1e30
        float pr = __expf(sc - mnew);
        lrun = lrun * corr + pr;
#pragma unroll
        for (int d = 0; d < 64; ++d)
          o[d] = o[d] * corr + pr * bf2f(Vs[s * 64 + d]);
        mrun = mnew;
      }
    }
    __syncthreads();
  }

  if (tid < 128) {
    float inv = 1.0f / lrun;
#pragma unroll
    for (int d = 0; d < 64; ++d)
      AO[(size_t)(mg * 128 + tid) * 1024 + h * 64 + d] = f2bf(o[d] * inv);
  }
}

// ---------------- residual + LayerNorm ----------------
__global__ __launch_bounds__(256) void ln_kernel(
    const float* __restrict__ X, const float* __restrict__ O,
    const float* __restrict__ g, const float* __restrict__ b,
    float* __restrict__ out) {
  int row = blockIdx.x;
  int tid = threadIdx.x;
  const float* xr = X + (size_t)row * 1024;
  const float* orr = O + (size_t)row * 1024;
  float4 xv = *(const float4*)(xr + tid * 4);
  float4 ov = *(const float4*)(orr + tid * 4);
  float v0 = xv.x + ov.x, v1 = xv.y + ov.y, v2 = xv.z + ov.z, v3 = xv.w + ov.w;
  float s = v0 + v1 + v2 + v3;
  float s2 = v0 * v0 + v1 * v1 + v2 * v2 + v3 * v3;
  for (int d = 1; d < 64; d <<= 1) {
    s += __shfl_xor(s, d);
    s2 += __shfl_xor(s2, d);
  }
  __shared__ float ps[4], ps2[4];
  int w = tid >> 6;
  if ((tid & 63) == 0) {
    ps[w] = s;
    ps2[w] = s2;
  }
  __syncthreads();
  s = ps[0] + ps[1] + ps[2] + ps[3];
  s2 = ps2[0] + ps2[1] + ps2[2] + ps2[3];
  float mu = s * (1.0f / 1024.0f);
  float var = s2 * (1.0f / 1024.0f) - mu * mu;
  float rstd = rsqrtf(var + 1e-5f);
  float4 gv = *(const float4*)(g + tid * 4);
  float4 bv = *(const float4*)(b + tid * 4);
  float4 ou;
  ou.x = (v0 - mu) * rstd * gv.x + bv.x;
  ou.y = (v1 - mu) * rstd * gv.y + bv.y;
  ou.z = (v2 - mu) * rstd * gv.z + bv.z;
  ou.w = (v3 - mu) * rstd * gv.w + bv.w;
  *(float4*)(out + (size_t)row * 1024 + tid * 4) = ou;
}

extern "C" void kernel_launch(void* const* d_in, const int* in_sizes, int n_in,
                              void* d_out, int out_size, void* d_ws, size_t ws_size,
                              hipStream_t stream) {
  const float* ent_t = (const float*)d_in[0];
  const float* ent_i = (const float*)d_in[1];
  const float* img_feat = (const float*)d_in[2];
  const float* txt_feat = (const float*)d_in[3];
  const int* img_mask = (const int*)d_in[4];
  const int* txt_mask = (const int*)d_in[5];
  const float* W[8];
  const float* Bv[8];
  for (int i = 0; i < 8; ++i) {
    W[i] = (const float*)d_in[6 + 2 * i];
    Bv[i] = (const float*)d_in[7 + 2 * i];
  }
  const float* g_t = (const float*)d_in[22];
  const float* beta_t = (const float*)d_in[23];
  const float* g_i = (const float*)d_in[24];
  const float* beta_i = (const float*)d_in[25];
  float* out = (float*)d_out;

  // ws layout — 56 MB peak (defensive vs unknown ws_size):
  //   [0,8M)   Wbf   4 converted weight matrices (current modality)
  //   [8,16M)  Qbf   [4096,1024] bf16
  //   [16,24M) AObf  [4096,1024] bf16
  //   [24,40M) Kc    chunk K [8*S,1024] bf16   (Of32 [4096,1024] f32 aliases after attn)
  //   [40,56M) Vc    chunk V
  char* ws = (char*)d_ws;
  u16* Wbf = (u16*)ws;
  u16* Qbf = (u16*)(ws + (8ull << 20));
  u16* AObf = (u16*)(ws + (16ull << 20));
  u16* Kc = (u16*)(ws + (24ull << 20));
  u16* Vc = (u16*)(ws + (40ull << 20));
  float* Of32 = (float*)(ws + (24ull << 20));  // aliases Kc (dead after attn)

  for (int mod = 0; mod < 2; ++mod) {
    const float* ent = mod ? ent_i : ent_t;
    const float* feat = mod ? img_feat : txt_feat;
    const int* msk = mod ? img_mask : txt_mask;
    int S = mod ? 768 : 1024;

    cvt_w_kernel<<<2048, 256, 0, stream>>>(W[mod * 4 + 0], W[mod * 4 + 1],
                                           W[mod * 4 + 2], W[mod * 4 + 3], Wbf);

    const u16* wq = Wbf + 0ull * 1048576;
    const u16* wk = Wbf + 1ull * 1048576;
    const u16* wv = Wbf + 2ull * 1048576;
    const u16* wo = Wbf + 3ull * 1048576;
    const float* bq = Bv[mod * 4 + 0];
    const float* bk = Bv[mod * 4 + 1];
    const float* bvv = Bv[mod * 4 + 2];
    const float* bo = Bv[mod * 4 + 3];

    gemm_bias_kernel<true, false><<<dim3(8, 32), 256, 0, stream>>>(ent, wq, bq, Qbf, 4096);

    int crows = 8 * S;  // rows per m-chunk (8 m's)
    for (int c = 0; c < 4; ++c) {
      const float* featc = feat + (size_t)c * 8 * S * 1024;
      gemm_bias_kernel<true, false><<<dim3(8, crows / 128), 256, 0, stream>>>(featc, wk, bk, Kc, crows);
      gemm_bias_kernel<true, false><<<dim3(8, crows / 128), 256, 0, stream>>>(featc, wv, bvv, Vc, crows);
      attn_simple_kernel<<<128, 256, 0, stream>>>(Qbf, Kc, Vc, msk, AObf, S, c * 8);
    }

    gemm_bias_kernel<false, true><<<dim3(8, 32), 256, 0, stream>>>(AObf, wo, bo, Of32, 4096);
    ln_kernel<<<4096, 256, 0, stream>>>(ent, Of32,
                                        mod ? g_i : g_t, mod ? beta_i : beta_t,
                                        out + (size_t)mod * 4194304);
  }
}

// Round 5
// 832.264 us; speedup vs baseline: 8.3811x; 8.3811x over previous
//
#include <hip/hip_runtime.h>
#include <stdint.h>

typedef unsigned short u16;
typedef __attribute__((ext_vector_type(8))) short short8;
typedef __attribute__((ext_vector_type(4))) float f32x4;

#define SWZ(r) (((r) & 7) << 4)
#define SCALE 0.125f

__device__ __forceinline__ u16 f2bf(float f) {
  unsigned int x = __float_as_uint(f);
  x += 0x7fffu + ((x >> 16) & 1u);
  return (u16)(x >> 16);
}

__device__ __forceinline__ float bf2f(u16 u) {
  return __uint_as_float(((unsigned int)u) << 16);
}

__device__ __forceinline__ f32x4 mfma16(short8 a, short8 b, f32x4 c) {
  return __builtin_amdgcn_mfma_f32_16x16x32_bf16(a, b, c, 0, 0, 0);
}

__device__ __forceinline__ void gload_lds16(const u16* g, u16* l) {
  __builtin_amdgcn_global_load_lds(
      (const __attribute__((address_space(1))) unsigned int*)g,
      (__attribute__((address_space(3))) unsigned int*)l, 16, 0, 0);
}

// ---------------- weight conversion: 4x [1024x1024] f32 -> bf16 ----------------
__global__ __launch_bounds__(256) void cvt_w_kernel(
    const float* __restrict__ s0, const float* __restrict__ s1,
    const float* __restrict__ s2, const float* __restrict__ s3,
    u16* __restrict__ dst) {
  int bx = blockIdx.x;
  int mi = bx >> 9;  // 512 blocks per matrix
  const float* s = s0;
  if (mi == 1) s = s1;
  else if (mi == 2) s = s2;
  else if (mi == 3) s = s3;
  size_t idx = (size_t)((bx & 511) * 256 + threadIdx.x) * 8;
  float4 a = *(const float4*)(s + idx);
  float4 b = *(const float4*)(s + idx + 4);
  short8 v;
  v[0] = (short)f2bf(a.x); v[1] = (short)f2bf(a.y);
  v[2] = (short)f2bf(a.z); v[3] = (short)f2bf(a.w);
  v[4] = (short)f2bf(b.x); v[5] = (short)f2bf(b.y);
  v[6] = (short)f2bf(b.z); v[7] = (short)f2bf(b.w);
  *(short8*)(dst + (size_t)mi * 1048576 + idx) = v;
}

// ---------------- GEMM: C[r,o] = sum_d A[r,d]*W[o,d] + bias[o] ----------------
// (unchanged from round 4 — HW-validated)
template <bool A_F32, bool OUT_F32>
__global__ __launch_bounds__(256, 2) void gemm_bias_kernel(
    const void* __restrict__ Av, const u16* __restrict__ B,
    const float* __restrict__ bias, void* __restrict__ Cv, int nrows) {
  __shared__ __attribute__((aligned(16))) u16 As[128 * 64];
  __shared__ __attribute__((aligned(16))) u16 Bs[128 * 64];
  const int tid = threadIdx.x;
  const int lane = tid & 63;
  const int w = tid >> 6;
  const int wr = w >> 1, wc = w & 1;
  const int l15 = lane & 15, lg = lane >> 4;
  const int brow = blockIdx.y * 128;
  const int bcol = blockIdx.x * 128;

  f32x4 acc[4][4] = {};

  for (int k0 = 0; k0 < 1024; k0 += 64) {
#pragma unroll
    for (int p = 0; p < 4; ++p) {
      int flat = p * 256 + tid;   // [0,1024)
      int row = flat >> 3;        // [0,128)
      int cb = (flat & 7) * 16;
      int scb = cb ^ SWZ(row);
      const u16* src = B + (size_t)(bcol + row) * 1024 + k0 + (scb >> 1);
      gload_lds16(src, Bs + (size_t)flat * 8);
    }
    if constexpr (A_F32) {
      const float* Af = (const float*)Av;
#pragma unroll
      for (int p = 0; p < 4; ++p) {
        int flat = p * 256 + tid;
        int row = flat >> 3;
        int c8 = flat & 7;
        const float* src = Af + (size_t)(brow + row) * 1024 + k0 + c8 * 8;
        float4 v0 = ((const float4*)src)[0];
        float4 v1 = ((const float4*)src)[1];
        short8 sv;
        sv[0] = (short)f2bf(v0.x); sv[1] = (short)f2bf(v0.y);
        sv[2] = (short)f2bf(v0.z); sv[3] = (short)f2bf(v0.w);
        sv[4] = (short)f2bf(v1.x); sv[5] = (short)f2bf(v1.y);
        sv[6] = (short)f2bf(v1.z); sv[7] = (short)f2bf(v1.w);
        *(short8*)((char*)As + row * 128 + ((c8 * 16) ^ SWZ(row))) = sv;
      }
    } else {
      const u16* Ab = (const u16*)Av;
#pragma unroll
      for (int p = 0; p < 4; ++p) {
        int flat = p * 256 + tid;
        int row = flat >> 3;
        int cb = (flat & 7) * 16;
        int scb = cb ^ SWZ(row);
        const u16* src = Ab + (size_t)(brow + row) * 1024 + k0 + (scb >> 1);
        gload_lds16(src, As + (size_t)flat * 8);
      }
    }
    __syncthreads();

    short8 af[4][2], bfr[4][2];
#pragma unroll
    for (int i = 0; i < 4; ++i) {
#pragma unroll
      for (int kk = 0; kk < 2; ++kk) {
        int ar = wr * 64 + i * 16 + l15;
        af[i][kk] = *(const short8*)((const char*)As + ar * 128 +
                                     ((kk * 64 + lg * 16) ^ SWZ(ar)));
        int br = wc * 64 + i * 16 + l15;
        bfr[i][kk] = *(const short8*)((const char*)Bs + br * 128 +
                                      ((kk * 64 + lg * 16) ^ SWZ(br)));
      }
    }
#pragma unroll
    for (int i = 0; i < 4; ++i)
#pragma unroll
      for (int j = 0; j < 4; ++j)
#pragma unroll
        for (int kk = 0; kk < 2; ++kk)
          acc[i][j] = mfma16(af[i][kk], bfr[j][kk], acc[i][j]);
    __syncthreads();
  }

#pragma unroll
  for (int j = 0; j < 4; ++j) {
    int col = bcol + wc * 64 + j * 16 + l15;
    float bv = bias[col];
#pragma unroll
    for (int i = 0; i < 4; ++i) {
      int row0 = brow + wr * 64 + i * 16 + lg * 4;
#pragma unroll
      for (int r = 0; r < 4; ++r) {
        float v = acc[i][j][r] + bv;
        if constexpr (OUT_F32)
          ((float*)Cv)[(size_t)(row0 + r) * 1024 + col] = v;
        else
          ((u16*)Cv)[(size_t)(row0 + r) * 1024 + col] = f2bf(v);
      }
    }
  }
}

// ---------------- MFMA flash attention per (m_local, h) ----------------
// Q: [4096,1024] bf16, Kp/Vp: chunk-local [(nm)*S,1024] bf16, mask: [M,S] int.
// 4 waves x 32 q-rows each; K,V tiles (64 kv) staged in LDS; P via wave-private
// swizzled LDS; online softmax per D-row; no infinities (bias = -1e30).
__global__ __launch_bounds__(256, 2) void attn_mfma_kernel(
    const u16* __restrict__ Q, const u16* __restrict__ Kp,
    const u16* __restrict__ Vp, const int* __restrict__ mask,
    u16* __restrict__ AO, int S, int mbase) {
  __shared__ __attribute__((aligned(16))) u16 Ks[64 * 64];
  __shared__ __attribute__((aligned(16))) u16 Vt[64 * 64];
  __shared__ __attribute__((aligned(16))) u16 Ps[4 * 32 * 64];
  __shared__ float mb[64];

  const int tid = threadIdx.x;
  const int lane = tid & 63;
  const int w = tid >> 6;
  const int ml = blockIdx.x >> 4;  // chunk-local m
  const int h = blockIdx.x & 15;
  const int mg = mbase + ml;       // global m
  const int l15 = lane & 15, lg = lane >> 4;

  // Q fragments in registers for the whole kernel (A-operand layout)
  short8 qf[2][2];
#pragma unroll
  for (int qb = 0; qb < 2; ++qb)
#pragma unroll
    for (int kk = 0; kk < 2; ++kk)
      qf[qb][kk] = *(const short8*)(Q + (size_t)(mg * 128 + w * 32 + qb * 16 + l15) * 1024 +
                                    h * 64 + kk * 32 + lg * 8);

  float mrun[2][4], lrun[2][4];
  f32x4 oacc[2][4] = {};
#pragma unroll
  for (int qb = 0; qb < 2; ++qb)
#pragma unroll
    for (int r = 0; r < 4; ++r) {
      mrun[qb][r] = -1e30f;
      lrun[qb][r] = 0.0f;
    }

  const size_t kvbase = (size_t)ml * S * 1024 + h * 64;

  for (int st = 0; st < S; st += 64) {
    if (tid < 64)
      mb[tid] = (mask[(size_t)mg * S + st + tid] > 0) ? 0.0f : -1e30f;
    // stage K tile [64 s][64 d], swizzled
#pragma unroll
    for (int p = 0; p < 2; ++p) {
      int flat = p * 256 + tid;
      int row = flat >> 3;
      int c = flat & 7;
      short8 v = *(const short8*)(Kp + kvbase + (size_t)(st + row) * 1024 + c * 8);
      *(short8*)((char*)Ks + row * 128 + ((c * 16) ^ SWZ(row))) = v;
    }
    // stage V transposed: Vt[d][s], swizzled (scalar scatter)
#pragma unroll
    for (int p = 0; p < 2; ++p) {
      int flat = p * 256 + tid;
      int srow = flat >> 3;
      int c = flat & 7;
      short8 v = *(const short8*)(Vp + kvbase + (size_t)(st + srow) * 1024 + c * 8);
#pragma unroll
      for (int j = 0; j < 8; ++j) {
        int dr = c * 8 + j;
        *(u16*)((char*)Vt + dr * 128 + ((srow * 2) ^ SWZ(dr))) = (u16)v[j];
      }
    }
    __syncthreads();

    // QK^T: A=Q tile, B=K tile (col = s)
    short8 kf[4][2];
#pragma unroll
    for (int sb = 0; sb < 4; ++sb)
#pragma unroll
      for (int kk = 0; kk < 2; ++kk) {
        int row = sb * 16 + l15;
        kf[sb][kk] = *(const short8*)((const char*)Ks + row * 128 +
                                      ((kk * 64 + lg * 16) ^ SWZ(row)));
      }
    f32x4 sc[2][4] = {};
#pragma unroll
    for (int qb = 0; qb < 2; ++qb)
#pragma unroll
      for (int sb = 0; sb < 4; ++sb)
#pragma unroll
        for (int kk = 0; kk < 2; ++kk)
          sc[qb][sb] = mfma16(qf[qb][kk], kf[sb][kk], sc[qb][sb]);

    float mbv[4];
#pragma unroll
    for (int sb = 0; sb < 4; ++sb) mbv[sb] = mb[sb * 16 + l15];

    // online softmax; lane's D-rows: q_local = qb*16 + lg*4 + r, s = sb*16 + l15
#pragma unroll
    for (int qb = 0; qb < 2; ++qb) {
#pragma unroll
      for (int r = 0; r < 4; ++r) {
        float s0 = sc[qb][0][r] * SCALE + mbv[0];
        float s1 = sc[qb][1][r] * SCALE + mbv[1];
        float s2 = sc[qb][2][r] * SCALE + mbv[2];
        float s3 = sc[qb][3][r] * SCALE + mbv[3];
        float t = fmaxf(fmaxf(s0, s1), fmaxf(s2, s3));
        for (int d = 1; d < 16; d <<= 1) t = fmaxf(t, __shfl_xor(t, d));
        float mnew = fmaxf(mrun[qb][r], t);
        float resc = __expf(mrun[qb][r] - mnew);
        float p0 = __expf(s0 - mnew);
        float p1 = __expf(s1 - mnew);
        float p2 = __expf(s2 - mnew);
        float p3 = __expf(s3 - mnew);
        float rs = p0 + p1 + p2 + p3;
        for (int d = 1; d < 16; d <<= 1) rs += __shfl_xor(rs, d);
        lrun[qb][r] = lrun[qb][r] * resc + rs;
        mrun[qb][r] = mnew;
#pragma unroll
        for (int db = 0; db < 4; ++db) oacc[qb][db][r] *= resc;
        int row = qb * 16 + lg * 4 + r;
        char* pbase = (char*)Ps + (w * 32 + row) * 128;
        int colb = 2 * l15;
        *(u16*)(pbase + ((0 * 32 + colb) ^ SWZ(row))) = f2bf(p0);
        *(u16*)(pbase + ((1 * 32 + colb) ^ SWZ(row))) = f2bf(p1);
        *(u16*)(pbase + ((2 * 32 + colb) ^ SWZ(row))) = f2bf(p2);
        *(u16*)(pbase + ((3 * 32 + colb) ^ SWZ(row))) = f2bf(p3);
      }
    }
    __syncthreads();  // full fence: P stores visible before P fragment loads

    // PV: A=P (row=q, k=s), B=V^T (col=d, k=s)
    short8 pf[2][2], vf[4][2];
#pragma unroll
    for (int qb = 0; qb < 2; ++qb)
#pragma unroll
      for (int kk = 0; kk < 2; ++kk) {
        int row = qb * 16 + l15;
        pf[qb][kk] = *(const short8*)((const char*)Ps + (w * 32 + row) * 128 +
                                      ((kk * 64 + lg * 16) ^ SWZ(row)));
      }
#pragma unroll
    for (int db = 0; db < 4; ++db)
#pragma unroll
      for (int kk = 0; kk < 2; ++kk) {
        int row = db * 16 + l15;
        vf[db][kk] = *(const short8*)((const char*)Vt + row * 128 +
                                      ((kk * 64 + lg * 16) ^ SWZ(row)));
      }
#pragma unroll
    for (int qb = 0; qb < 2; ++qb)
#pragma unroll
      for (int db = 0; db < 4; ++db)
#pragma unroll
        for (int kk = 0; kk < 2; ++kk)
          oacc[qb][db] = mfma16(pf[qb][kk], vf[db][kk], oacc[qb][db]);
    __syncthreads();
  }

#pragma unroll
  for (int qb = 0; qb < 2; ++qb)
#pragma unroll
    for (int db = 0; db < 4; ++db)
#pragma unroll
      for (int r = 0; r < 4; ++r) {
        int grow = mg * 128 + w * 32 + qb * 16 + lg * 4 + r;
        int gcol = h * 64 + db * 16 + l15;
        float v = oacc[qb][db][r] / lrun[qb][r];
        AO[(size_t)grow * 1024 + gcol] = f2bf(v);
      }
}

// ---------------- residual + LayerNorm ----------------
__global__ __launch_bounds__(256) void ln_kernel(
    const float* __restrict__ X, const float* __restrict__ O,
    const float* __restrict__ g, const float* __restrict__ b,
    float* __restrict__ out) {
  int row = blockIdx.x;
  int tid = threadIdx.x;
  const float* xr = X + (size_t)row * 1024;
  const float* orr = O + (size_t)row * 1024;
  float4 xv = *(const float4*)(xr + tid * 4);
  float4 ov = *(const float4*)(orr + tid * 4);
  float v0 = xv.x + ov.x, v1 = xv.y + ov.y, v2 = xv.z + ov.z, v3 = xv.w + ov.w;
  float s = v0 + v1 + v2 + v3;
  float s2 = v0 * v0 + v1 * v1 + v2 * v2 + v3 * v3;
  for (int d = 1; d < 64; d <<= 1) {
    s += __shfl_xor(s, d);
    s2 += __shfl_xor(s2, d);
  }
  __shared__ float ps[4], ps2[4];
  int w = tid >> 6;
  if ((tid & 63) == 0) {
    ps[w] = s;
    ps2[w] = s2;
  }
  __syncthreads();
  s = ps[0] + ps[1] + ps[2] + ps[3];
  s2 = ps2[0] + ps2[1] + ps2[2] + ps2[3];
  float mu = s * (1.0f / 1024.0f);
  float var = s2 * (1.0f / 1024.0f) - mu * mu;
  float rstd = rsqrtf(var + 1e-5f);
  float4 gv = *(const float4*)(g + tid * 4);
  float4 bv = *(const float4*)(b + tid * 4);
  float4 ou;
  ou.x = (v0 - mu) * rstd * gv.x + bv.x;
  ou.y = (v1 - mu) * rstd * gv.y + bv.y;
  ou.z = (v2 - mu) * rstd * gv.z + bv.z;
  ou.w = (v3 - mu) * rstd * gv.w + bv.w;
  *(float4*)(out + (size_t)row * 1024 + tid * 4) = ou;
}

extern "C" void kernel_launch(void* const* d_in, const int* in_sizes, int n_in,
                              void* d_out, int out_size, void* d_ws, size_t ws_size,
                              hipStream_t stream) {
  const float* ent_t = (const float*)d_in[0];
  const float* ent_i = (const float*)d_in[1];
  const float* img_feat = (const float*)d_in[2];
  const float* txt_feat = (const float*)d_in[3];
  const int* img_mask = (const int*)d_in[4];
  const int* txt_mask = (const int*)d_in[5];
  const float* W[8];
  const float* Bv[8];
  for (int i = 0; i < 8; ++i) {
    W[i] = (const float*)d_in[6 + 2 * i];
    Bv[i] = (const float*)d_in[7 + 2 * i];
  }
  const float* g_t = (const float*)d_in[22];
  const float* beta_t = (const float*)d_in[23];
  const float* g_i = (const float*)d_in[24];
  const float* beta_i = (const float*)d_in[25];
  float* out = (float*)d_out;

  // chunk count over m (32 rows of 128 q / S kv each), chosen from ws_size:
  //   layout: Wbf 8M | Qbf 8M | AObf 8M | Kc X | Vc X, X = 64MB/nc (text sizing)
  //   Of32 (16MB) aliases Kc (dead after attention).  need = 24M + 2X.
  int nc = 4;
  if (ws_size >= (152ull << 20)) nc = 1;
  else if (ws_size >= (88ull << 20)) nc = 2;
  size_t X = (64ull << 20) / nc;

  char* ws = (char*)d_ws;
  u16* Wbf = (u16*)ws;
  u16* Qbf = (u16*)(ws + (8ull << 20));
  u16* AObf = (u16*)(ws + (16ull << 20));
  u16* Kc = (u16*)(ws + (24ull << 20));
  u16* Vc = (u16*)(ws + (24ull << 20) + X);
  float* Of32 = (float*)(ws + (24ull << 20));  // aliases Kc

  const int mpc = 32 / nc;  // m's per chunk

  for (int mod = 0; mod < 2; ++mod) {
    const float* ent = mod ? ent_i : ent_t;
    const float* feat = mod ? img_feat : txt_feat;
    const int* msk = mod ? img_mask : txt_mask;
    int S = mod ? 768 : 1024;

    cvt_w_kernel<<<2048, 256, 0, stream>>>(W[mod * 4 + 0], W[mod * 4 + 1],
                                           W[mod * 4 + 2], W[mod * 4 + 3], Wbf);

    const u16* wq = Wbf + 0ull * 1048576;
    const u16* wk = Wbf + 1ull * 1048576;
    const u16* wv = Wbf + 2ull * 1048576;
    const u16* wo = Wbf + 3ull * 1048576;
    const float* bq = Bv[mod * 4 + 0];
    const float* bk = Bv[mod * 4 + 1];
    const float* bvv = Bv[mod * 4 + 2];
    const float* bo = Bv[mod * 4 + 3];

    gemm_bias_kernel<true, false><<<dim3(8, 32), 256, 0, stream>>>(ent, wq, bq, Qbf, 4096);

    int crows = mpc * S;  // rows per chunk
    for (int c = 0; c < nc; ++c) {
      const float* featc = feat + (size_t)c * mpc * S * 1024;
      gemm_bias_kernel<true, false><<<dim3(8, crows / 128), 256, 0, stream>>>(featc, wk, bk, Kc, crows);
      gemm_bias_kernel<true, false><<<dim3(8, crows / 128), 256, 0, stream>>>(featc, wv, bvv, Vc, crows);
      attn_mfma_kernel<<<mpc * 16, 256, 0, stream>>>(Qbf, Kc, Vc, msk, AObf, S, c * mpc);
    }

    gemm_bias_kernel<false, true><<<dim3(8, 32), 256, 0, stream>>>(AObf, wo, bo, Of32, 4096);
    ln_kernel<<<4096, 256, 0, stream>>>(ent, Of32,
                                        mod ? g_i : g_t, mod ? beta_i : beta_t,
                                        out + (size_t)mod * 4194304);
  }
}

// Round 6
// 626.486 us; speedup vs baseline: 11.1340x; 1.3285x over previous
//
#include <hip/hip_runtime.h>
#include <stdint.h>

typedef unsigned short u16;
typedef __attribute__((ext_vector_type(8))) short short8;
typedef __attribute__((ext_vector_type(4))) float f32x4;

#define SWZ(r) (((r) & 7) << 4)
#define SCALE 0.125f

__device__ __forceinline__ u16 f2bf(float f) {
  unsigned int x = __float_as_uint(f);
  x += 0x7fffu + ((x >> 16) & 1u);
  return (u16)(x >> 16);
}

__device__ __forceinline__ f32x4 mfma16(short8 a, short8 b, f32x4 c) {
  return __builtin_amdgcn_mfma_f32_16x16x32_bf16(a, b, c, 0, 0, 0);
}

__device__ __forceinline__ void gload_lds16(const u16* g, u16* l) {
  __builtin_amdgcn_global_load_lds(
      (const __attribute__((address_space(1))) unsigned int*)g,
      (__attribute__((address_space(3))) unsigned int*)l, 16, 0, 0);
}

// XCD-chunked bijective swizzle (nwg % 8 == 0 by construction here):
// blocks resident on one XCD get a contiguous logical range -> L2 reuse.
__device__ __forceinline__ int xcd_swz(int bid, int nwg) {
  int cpx = nwg >> 3;
  return (bid & 7) * cpx + (bid >> 3);
}

// ---------------- weight conversion: 4x [1024x1024] f32 -> bf16 ----------------
__global__ __launch_bounds__(256) void cvt_w_kernel(
    const float* __restrict__ s0, const float* __restrict__ s1,
    const float* __restrict__ s2, const float* __restrict__ s3,
    u16* __restrict__ dst) {
  int bx = blockIdx.x;
  int mi = bx >> 9;  // 512 blocks per matrix
  const float* s = s0;
  if (mi == 1) s = s1;
  else if (mi == 2) s = s2;
  else if (mi == 3) s = s3;
  size_t idx = (size_t)((bx & 511) * 256 + threadIdx.x) * 8;
  float4 a = *(const float4*)(s + idx);
  float4 b = *(const float4*)(s + idx + 4);
  short8 v;
  v[0] = (short)f2bf(a.x); v[1] = (short)f2bf(a.y);
  v[2] = (short)f2bf(a.z); v[3] = (short)f2bf(a.w);
  v[4] = (short)f2bf(b.x); v[5] = (short)f2bf(b.y);
  v[6] = (short)f2bf(b.z); v[7] = (short)f2bf(b.w);
  *(short8*)(dst + (size_t)mi * 1048576 + idx) = v;
}

// ---------------- GEMM: C[r,o] = sum_d A[r,d]*W[o,d] + bias[o] ----------------
// A: [rows,1024] (f32 or bf16); W: [NCOL? ,1024] bf16 row-major where NCOL =
// gridDim.x*128 (1024 or 2048 fused KV); C: [rows, ldc]. bias split at col 1024.
// tile 128x128, BK=64, 4 waves, 16x16x32 bf16 MFMA, XOR-swizzled LDS,
// XCD-chunked block swizzle.
template <bool A_F32, bool OUT_F32>
__global__ __launch_bounds__(256, 2) void gemm_bias_kernel(
    const void* __restrict__ Av, const u16* __restrict__ B,
    const float* __restrict__ bias0, const float* __restrict__ bias1,
    void* __restrict__ Cv, int ldc) {
  __shared__ __attribute__((aligned(16))) u16 As[128 * 64];
  __shared__ __attribute__((aligned(16))) u16 Bs[128 * 64];
  const int tid = threadIdx.x;
  const int lane = tid & 63;
  const int w = tid >> 6;
  const int wr = w >> 1, wc = w & 1;
  const int l15 = lane & 15, lg = lane >> 4;

  const int nwg = gridDim.x * gridDim.y;
  const int lid = xcd_swz(blockIdx.y * gridDim.x + blockIdx.x, nwg);
  const int bx = lid % gridDim.x;
  const int by = lid / gridDim.x;
  const int brow = by * 128;
  const int bcol = bx * 128;

  f32x4 acc[4][4] = {};

  for (int k0 = 0; k0 < 1024; k0 += 64) {
#pragma unroll
    for (int p = 0; p < 4; ++p) {
      int flat = p * 256 + tid;   // [0,1024)
      int row = flat >> 3;        // [0,128)
      int cb = (flat & 7) * 16;
      int scb = cb ^ SWZ(row);
      const u16* src = B + (size_t)(bcol + row) * 1024 + k0 + (scb >> 1);
      gload_lds16(src, Bs + (size_t)flat * 8);
    }
    if constexpr (A_F32) {
      const float* Af = (const float*)Av;
#pragma unroll
      for (int p = 0; p < 4; ++p) {
        int flat = p * 256 + tid;
        int row = flat >> 3;
        int c8 = flat & 7;
        const float* src = Af + (size_t)(brow + row) * 1024 + k0 + c8 * 8;
        float4 v0 = ((const float4*)src)[0];
        float4 v1 = ((const float4*)src)[1];
        short8 sv;
        sv[0] = (short)f2bf(v0.x); sv[1] = (short)f2bf(v0.y);
        sv[2] = (short)f2bf(v0.z); sv[3] = (short)f2bf(v0.w);
        sv[4] = (short)f2bf(v1.x); sv[5] = (short)f2bf(v1.y);
        sv[6] = (short)f2bf(v1.z); sv[7] = (short)f2bf(v1.w);
        *(short8*)((char*)As + row * 128 + ((c8 * 16) ^ SWZ(row))) = sv;
      }
    } else {
      const u16* Ab = (const u16*)Av;
#pragma unroll
      for (int p = 0; p < 4; ++p) {
        int flat = p * 256 + tid;
        int row = flat >> 3;
        int cb = (flat & 7) * 16;
        int scb = cb ^ SWZ(row);
        const u16* src = Ab + (size_t)(brow + row) * 1024 + k0 + (scb >> 1);
        gload_lds16(src, As + (size_t)flat * 8);
      }
    }
    __syncthreads();

    short8 af[4][2], bfr[4][2];
#pragma unroll
    for (int i = 0; i < 4; ++i) {
#pragma unroll
      for (int kk = 0; kk < 2; ++kk) {
        int ar = wr * 64 + i * 16 + l15;
        af[i][kk] = *(const short8*)((const char*)As + ar * 128 +
                                     ((kk * 64 + lg * 16) ^ SWZ(ar)));
        int br = wc * 64 + i * 16 + l15;
        bfr[i][kk] = *(const short8*)((const char*)Bs + br * 128 +
                                      ((kk * 64 + lg * 16) ^ SWZ(br)));
      }
    }
#pragma unroll
    for (int i = 0; i < 4; ++i)
#pragma unroll
      for (int j = 0; j < 4; ++j)
#pragma unroll
        for (int kk = 0; kk < 2; ++kk)
          acc[i][j] = mfma16(af[i][kk], bfr[j][kk], acc[i][j]);
    __syncthreads();
  }

#pragma unroll
  for (int j = 0; j < 4; ++j) {
    int col = bcol + wc * 64 + j * 16 + l15;
    const float* bp = (col < 1024) ? bias0 : bias1;
    float bv = bp[col & 1023];
#pragma unroll
    for (int i = 0; i < 4; ++i) {
      int row0 = brow + wr * 64 + i * 16 + lg * 4;
#pragma unroll
      for (int r = 0; r < 4; ++r) {
        float v = acc[i][j][r] + bv;
        if constexpr (OUT_F32)
          ((float*)Cv)[(size_t)(row0 + r) * ldc + col] = v;
        else
          ((u16*)Cv)[(size_t)(row0 + r) * ldc + col] = f2bf(v);
      }
    }
  }
}

// ---------------- MFMA flash attention per (m_local, h) ----------------
// Q: [4096,1024] bf16; KV: chunk-local [(mpc)*S, 2048] bf16 (K cols 0..1023,
// V cols 1024..2047); mask: [M,S] int. 4 waves x 32 q-rows.
__global__ __launch_bounds__(256, 2) void attn_mfma_kernel(
    const u16* __restrict__ Q, const u16* __restrict__ KV,
    const int* __restrict__ mask, u16* __restrict__ AO, int S, int mbase) {
  __shared__ __attribute__((aligned(16))) u16 Ks[64 * 64];
  __shared__ __attribute__((aligned(16))) u16 Vt[64 * 64];
  __shared__ __attribute__((aligned(16))) u16 Ps[4 * 32 * 64];
  __shared__ float mb[64];

  const int tid = threadIdx.x;
  const int lane = tid & 63;
  const int w = tid >> 6;
  const int lid = xcd_swz(blockIdx.x, gridDim.x);
  const int ml = lid >> 4;   // chunk-local m
  const int h = lid & 15;
  const int mg = mbase + ml; // global m
  const int l15 = lane & 15, lg = lane >> 4;

  // Q fragments in registers for the whole kernel (A-operand layout)
  short8 qf[2][2];
#pragma unroll
  for (int qb = 0; qb < 2; ++qb)
#pragma unroll
    for (int kk = 0; kk < 2; ++kk)
      qf[qb][kk] = *(const short8*)(Q + (size_t)(mg * 128 + w * 32 + qb * 16 + l15) * 1024 +
                                    h * 64 + kk * 32 + lg * 8);

  float mrun[2][4], lrun[2][4];
  f32x4 oacc[2][4] = {};
#pragma unroll
  for (int qb = 0; qb < 2; ++qb)
#pragma unroll
    for (int r = 0; r < 4; ++r) {
      mrun[qb][r] = -1e30f;
      lrun[qb][r] = 0.0f;
    }

  const size_t kvbase = (size_t)ml * S * 2048 + h * 64;

  for (int st = 0; st < S; st += 64) {
    if (tid < 64)
      mb[tid] = (mask[(size_t)mg * S + st + tid] > 0) ? 0.0f : -1e30f;
    // stage K tile [64 s][64 d], swizzled
#pragma unroll
    for (int p = 0; p < 2; ++p) {
      int flat = p * 256 + tid;
      int row = flat >> 3;
      int c = flat & 7;
      short8 v = *(const short8*)(KV + kvbase + (size_t)(st + row) * 2048 + c * 8);
      *(short8*)((char*)Ks + row * 128 + ((c * 16) ^ SWZ(row))) = v;
    }
    // stage V transposed: Vt[d][s], swizzled (scalar scatter)
#pragma unroll
    for (int p = 0; p < 2; ++p) {
      int flat = p * 256 + tid;
      int srow = flat >> 3;
      int c = flat & 7;
      short8 v = *(const short8*)(KV + kvbase + 1024 + (size_t)(st + srow) * 2048 + c * 8);
#pragma unroll
      for (int j = 0; j < 8; ++j) {
        int dr = c * 8 + j;
        *(u16*)((char*)Vt + dr * 128 + ((srow * 2) ^ SWZ(dr))) = (u16)v[j];
      }
    }
    __syncthreads();

    // QK^T: A=Q tile, B=K tile (col = s)
    short8 kf[4][2];
#pragma unroll
    for (int sb = 0; sb < 4; ++sb)
#pragma unroll
      for (int kk = 0; kk < 2; ++kk) {
        int row = sb * 16 + l15;
        kf[sb][kk] = *(const short8*)((const char*)Ks + row * 128 +
                                      ((kk * 64 + lg * 16) ^ SWZ(row)));
      }
    f32x4 sc[2][4] = {};
#pragma unroll
    for (int qb = 0; qb < 2; ++qb)
#pragma unroll
      for (int sb = 0; sb < 4; ++sb)
#pragma unroll
        for (int kk = 0; kk < 2; ++kk)
          sc[qb][sb] = mfma16(qf[qb][kk], kf[sb][kk], sc[qb][sb]);

    float mbv[4];
#pragma unroll
    for (int sb = 0; sb < 4; ++sb) mbv[sb] = mb[sb * 16 + l15];

    // online softmax; lane's D-rows: q_local = qb*16 + lg*4 + r, s = sb*16 + l15
#pragma unroll
    for (int qb = 0; qb < 2; ++qb) {
#pragma unroll
      for (int r = 0; r < 4; ++r) {
        float s0 = sc[qb][0][r] * SCALE + mbv[0];
        float s1 = sc[qb][1][r] * SCALE + mbv[1];
        float s2 = sc[qb][2][r] * SCALE + mbv[2];
        float s3 = sc[qb][3][r] * SCALE + mbv[3];
        float t = fmaxf(fmaxf(s0, s1), fmaxf(s2, s3));
        for (int d = 1; d < 16; d <<= 1) t = fmaxf(t, __shfl_xor(t, d));
        float mnew = fmaxf(mrun[qb][r], t);
        float resc = __expf(mrun[qb][r] - mnew);
        float p0 = __expf(s0 - mnew);
        float p1 = __expf(s1 - mnew);
        float p2 = __expf(s2 - mnew);
        float p3 = __expf(s3 - mnew);
        float rs = p0 + p1 + p2 + p3;
        for (int d = 1; d < 16; d <<= 1) rs += __shfl_xor(rs, d);
        lrun[qb][r] = lrun[qb][r] * resc + rs;
        mrun[qb][r] = mnew;
#pragma unroll
        for (int db = 0; db < 4; ++db) oacc[qb][db][r] *= resc;
        int row = qb * 16 + lg * 4 + r;
        char* pbase = (char*)Ps + (w * 32 + row) * 128;
        int colb = 2 * l15;
        *(u16*)(pbase + ((0 * 32 + colb) ^ SWZ(row))) = f2bf(p0);
        *(u16*)(pbase + ((1 * 32 + colb) ^ SWZ(row))) = f2bf(p1);
        *(u16*)(pbase + ((2 * 32 + colb) ^ SWZ(row))) = f2bf(p2);
        *(u16*)(pbase + ((3 * 32 + colb) ^ SWZ(row))) = f2bf(p3);
      }
    }
    __syncthreads();  // full fence: P stores visible before P fragment loads

    // PV: A=P (row=q, k=s), B=V^T (col=d, k=s)
    short8 pf[2][2], vf[4][2];
#pragma unroll
    for (int qb = 0; qb < 2; ++qb)
#pragma unroll
      for (int kk = 0; kk < 2; ++kk) {
        int row = qb * 16 + l15;
        pf[qb][kk] = *(const short8*)((const char*)Ps + (w * 32 + row) * 128 +
                                      ((kk * 64 + lg * 16) ^ SWZ(row)));
      }
#pragma unroll
    for (int db = 0; db < 4; ++db)
#pragma unroll
      for (int kk = 0; kk < 2; ++kk) {
        int row = db * 16 + l15;
        vf[db][kk] = *(const short8*)((const char*)Vt + row * 128 +
                                      ((kk * 64 + lg * 16) ^ SWZ(row)));
      }
#pragma unroll
    for (int qb = 0; qb < 2; ++qb)
#pragma unroll
      for (int db = 0; db < 4; ++db)
#pragma unroll
        for (int kk = 0; kk < 2; ++kk)
          oacc[qb][db] = mfma16(pf[qb][kk], vf[db][kk], oacc[qb][db]);
    __syncthreads();
  }

#pragma unroll
  for (int qb = 0; qb < 2; ++qb)
#pragma unroll
    for (int db = 0; db < 4; ++db)
#pragma unroll
      for (int r = 0; r < 4; ++r) {
        int grow = mg * 128 + w * 32 + qb * 16 + lg * 4 + r;
        int gcol = h * 64 + db * 16 + l15;
        float v = oacc[qb][db][r] / lrun[qb][r];
        AO[(size_t)grow * 1024 + gcol] = f2bf(v);
      }
}

// ---------------- residual + LayerNorm ----------------
__global__ __launch_bounds__(256) void ln_kernel(
    const float* __restrict__ X, const float* __restrict__ O,
    const float* __restrict__ g, const float* __restrict__ b,
    float* __restrict__ out) {
  int row = blockIdx.x;
  int tid = threadIdx.x;
  const float* xr = X + (size_t)row * 1024;
  const float* orr = O + (size_t)row * 1024;
  float4 xv = *(const float4*)(xr + tid * 4);
  float4 ov = *(const float4*)(orr + tid * 4);
  float v0 = xv.x + ov.x, v1 = xv.y + ov.y, v2 = xv.z + ov.z, v3 = xv.w + ov.w;
  float s = v0 + v1 + v2 + v3;
  float s2 = v0 * v0 + v1 * v1 + v2 * v2 + v3 * v3;
  for (int d = 1; d < 64; d <<= 1) {
    s += __shfl_xor(s, d);
    s2 += __shfl_xor(s2, d);
  }
  __shared__ float ps[4], ps2[4];
  int w = tid >> 6;
  if ((tid & 63) == 0) {
    ps[w] = s;
    ps2[w] = s2;
  }
  __syncthreads();
  s = ps[0] + ps[1] + ps[2] + ps[3];
  s2 = ps2[0] + ps2[1] + ps2[2] + ps2[3];
  float mu = s * (1.0f / 1024.0f);
  float var = s2 * (1.0f / 1024.0f) - mu * mu;
  float rstd = rsqrtf(var + 1e-5f);
  float4 gv = *(const float4*)(g + tid * 4);
  float4 bv = *(const float4*)(b + tid * 4);
  float4 ou;
  ou.x = (v0 - mu) * rstd * gv.x + bv.x;
  ou.y = (v1 - mu) * rstd * gv.y + bv.y;
  ou.z = (v2 - mu) * rstd * gv.z + bv.z;
  ou.w = (v3 - mu) * rstd * gv.w + bv.w;
  *(float4*)(out + (size_t)row * 1024 + tid * 4) = ou;
}

extern "C" void kernel_launch(void* const* d_in, const int* in_sizes, int n_in,
                              void* d_out, int out_size, void* d_ws, size_t ws_size,
                              hipStream_t stream) {
  const float* ent_t = (const float*)d_in[0];
  const float* ent_i = (const float*)d_in[1];
  const float* img_feat = (const float*)d_in[2];
  const float* txt_feat = (const float*)d_in[3];
  const int* img_mask = (const int*)d_in[4];
  const int* txt_mask = (const int*)d_in[5];
  const float* W[8];
  const float* Bv[8];
  for (int i = 0; i < 8; ++i) {
    W[i] = (const float*)d_in[6 + 2 * i];
    Bv[i] = (const float*)d_in[7 + 2 * i];
  }
  const float* g_t = (const float*)d_in[22];
  const float* beta_t = (const float*)d_in[23];
  const float* g_i = (const float*)d_in[24];
  const float* beta_i = (const float*)d_in[25];
  float* out = (float*)d_out;

  // ws layout (same thresholds as round 4, KV fused = K+V bytes):
  //   [0,8M)   Wbf  4 converted weight matrices (wq|wk|wv|wo, wk|wv contiguous)
  //   [8,16M)  Qbf  [4096,1024] bf16
  //   [16,24M) AObf [4096,1024] bf16
  //   [24M,..) KVc  chunk [(32/nc)*S, 2048] bf16 (<=128MB/nc)
  //            Of32 [4096,1024] f32 aliases KVc (dead after attn)
  int nc = 4;
  if (ws_size >= (152ull << 20)) nc = 1;
  else if (ws_size >= (88ull << 20)) nc = 2;

  char* ws = (char*)d_ws;
  u16* Wbf = (u16*)ws;
  u16* Qbf = (u16*)(ws + (8ull << 20));
  u16* AObf = (u16*)(ws + (16ull << 20));
  u16* KVc = (u16*)(ws + (24ull << 20));
  float* Of32 = (float*)(ws + (24ull << 20));  // aliases KVc

  const int mpc = 32 / nc;  // m's per chunk

  for (int mod = 0; mod < 2; ++mod) {
    const float* ent = mod ? ent_i : ent_t;
    const float* feat = mod ? img_feat : txt_feat;
    const int* msk = mod ? img_mask : txt_mask;
    int S = mod ? 768 : 1024;

    cvt_w_kernel<<<2048, 256, 0, stream>>>(W[mod * 4 + 0], W[mod * 4 + 1],
                                           W[mod * 4 + 2], W[mod * 4 + 3], Wbf);

    const u16* wq = Wbf + 0ull * 1048576;
    const u16* wkv = Wbf + 1ull * 1048576;  // wk|wv contiguous = [2048,1024]
    const u16* wo = Wbf + 3ull * 1048576;
    const float* bq = Bv[mod * 4 + 0];
    const float* bk = Bv[mod * 4 + 1];
    const float* bvv = Bv[mod * 4 + 2];
    const float* bo = Bv[mod * 4 + 3];

    gemm_bias_kernel<true, false><<<dim3(8, 32), 256, 0, stream>>>(
        ent, wq, bq, bq, Qbf, 1024);

    int crows = mpc * S;  // rows per chunk
    for (int c = 0; c < nc; ++c) {
      const float* featc = feat + (size_t)c * mpc * S * 1024;
      gemm_bias_kernel<true, false><<<dim3(16, crows / 128), 256, 0, stream>>>(
          featc, wkv, bk, bvv, KVc, 2048);
      attn_mfma_kernel<<<mpc * 16, 256, 0, stream>>>(Qbf, KVc, msk, AObf, S, c * mpc);
    }

    gemm_bias_kernel<false, true><<<dim3(8, 32), 256, 0, stream>>>(
        AObf, wo, bo, bo, Of32, 1024);
    ln_kernel<<<4096, 256, 0, stream>>>(ent, Of32,
                                        mod ? g_i : g_t, mod ? beta_i : beta_t,
                                        out + (size_t)mod * 4194304);
  }
}